// Round 3
// baseline (892.668 us; speedup 1.0000x reference)
//
#include <hip/hip_runtime.h>
#include <stdint.h>

typedef short bf8 __attribute__((ext_vector_type(8)));   // 8 bf16 (4 VGPRs)
typedef float f4  __attribute__((ext_vector_type(4)));   // MFMA acc
typedef unsigned short u16;

#define LOG2E 1.4426950408889634f

// float -> bf16 (RNE)
__device__ __forceinline__ u16 f2bf(float f){
  uint32_t u = __builtin_bit_cast(uint32_t, f);
  u += 0x7fffu + ((u >> 16) & 1u);
  return (u16)(u >> 16);
}
// sigmoid of a value pre-scaled by log2(e):  1/(1+2^-a)
__device__ __forceinline__ float sigm_ps(float a){
  return __builtin_amdgcn_rcpf(1.0f + __builtin_amdgcn_exp2f(-a));
}

// ---------------------------------------------------------------------------
// Prep: prescaled bf16 concatenated weights W0c[512][160]=[Whh0|Wih0|0],
// W1c[512][256]=[Whh1|Wih1]; rows scaled by log2e (i,f,o) / 2*log2e (g);
// combined prescaled biases.
// ---------------------------------------------------------------------------
__global__ void prep_kernel(const float* __restrict__ Wih0, const float* __restrict__ Whh0,
                            const float* __restrict__ bih0, const float* __restrict__ bhh0,
                            const float* __restrict__ Wih1, const float* __restrict__ Whh1,
                            const float* __restrict__ bih1, const float* __restrict__ bhh1,
                            u16* __restrict__ W0c, u16* __restrict__ W1c,
                            float* __restrict__ bias0, float* __restrict__ bias1){
  int g = blockIdx.x;      // gate row 0..511
  int t = threadIdx.x;     // 0..63
  float s = (g >= 256 && g < 384) ? 2.0f * LOG2E : LOG2E;
  for(int k = t; k < 160; k += 64){
    float v = 0.0f;
    if(k < 128)      v = Whh0[g*128 + k];
    else if(k < 146) v = Wih0[g*18 + (k-128)];
    W0c[g*160 + k] = f2bf(v * s);
  }
  for(int k = t; k < 256; k += 64){
    float v = (k < 128) ? Whh1[g*128 + k] : Wih1[g*128 + (k-128)];
    W1c[g*256 + k] = f2bf(v * s);
  }
  if(t == 0){
    bias0[g] = (bih0[g] + bhh0[g]) * s;
    bias1[g] = (bih1[g] + bhh1[g]) * s;
  }
}

// ---------------------------------------------------------------------------
// Persistent LSTM layer, single barrier per step.
// 256 blocks x 512 threads; block owns batch rows {2b, 2b+1}.
//   L0: A=[h(128)|x_t(18)|0pad]  K=160 (KT=5)
//   L1: A=[h2(128)|h1_t(128)]    K=256 (KT=8)
// Wave w covers gate cols q*128+[16w,16w+16). D-layout: col=lane&15,
// row=(lane>>4)*4+reg -> lanes 0-15 hold rows 0,1 in regs 0,1, so the
// pointwise update runs IN-REGISTER in the producing wave (no gate LDS
// round-trip). Abuf double-buffered: read buf[t&1], write buf[t^1];
// ONE __syncthreads per step.
// ---------------------------------------------------------------------------
template<int KT, int RS, bool IS_L0>
__global__ __launch_bounds__(512, 2)
void lstm_kernel(const u16* __restrict__ Wc, const float* __restrict__ bias,
                 const float* __restrict__ xin,        // L0 input (B,T,18) f32
                 const u16*   __restrict__ h1in,       // L1 input (B,T,128) bf16
                 u16*         __restrict__ h1out,      // L0 output (B,T,128) bf16
                 const float* __restrict__ Wfc1, const float* __restrict__ bfc1,
                 const float* __restrict__ Wfc2, const float* __restrict__ bfc2,
                 float* __restrict__ out)              // L1 only: (512,) f32
{
  constexpr int K = KT * 32;
  __shared__ __align__(16) u16  Abuf[2][2 * RS];   // double-buffered A rows
  __shared__ __align__(16) float hfin[256];        // FC head staging (L1)

  const int tid  = threadIdx.x;
  const int wave = tid >> 6;
  const int lane = tid & 63;
  const int quad = lane >> 4;
  const int l15  = lane & 15;
  const int bid  = blockIdx.x;
  const int j0   = 16*wave + l15;                  // gate column this lane owns

  // ---- persistent B fragments: lane holds B[k=quad*8+j][n] = Wc[n][k]
  bf8 Bf[4][KT];
#pragma unroll
  for(int q = 0; q < 4; q++){
    int n = q*128 + j0;
#pragma unroll
    for(int kt = 0; kt < KT; kt++){
      Bf[q][kt] = *(const bf8*)(Wc + n*K + kt*32 + quad*8);
    }
  }
  float b4[4];
#pragma unroll
  for(int q = 0; q < 4; q++) b4[q] = bias[q*128 + j0];

  // staging lane mapping: lanes >=16, sidx = wave + 8*(lane-16)
  const int sidx = (lane >= 16) ? (wave + 8*(lane - 16)) : 0x7fffffff;

  float c0 = 0.f, c1 = 0.f, h0r = 0.f, h1r = 0.f;

  // ---- init both buffers to zero, stage t=0 input into buf0
  for(int i = tid; i < 2*2*RS; i += 512) ((u16*)Abuf)[i] = 0;
  __syncthreads();
  if(IS_L0){
    if(tid < 36){
      int m = tid/18, kk = tid - 18*m;
      Abuf[0][m*RS + 128 + kk] = f2bf(xin[((2*bid + m)*512)*18 + kk]);
    }
  } else {
    if(tid < 32){
      int m = tid >> 4, ch = tid & 15;
      *(uint4*)&Abuf[0][m*RS + 128 + ch*8] =
          *(const uint4*)(h1in + ((2*bid + m)*512)*128 + ch*8);
    }
  }
  __syncthreads();

  for(int t = 0; t < 512; t++){
    const int cur = t & 1, nxt = cur ^ 1;

    // ---- prefetch t+1 input into registers (staging lanes)
    float xv = 0.0f; uint4 pv = {0u,0u,0u,0u};
    int sm = 0, sk = 0;
    if(t < 511){
      if(IS_L0){
        if(sidx < 36){
          sm = sidx/18; sk = sidx - 18*sm;
          xv = xin[((2*bid + sm)*512 + t + 1)*18 + sk];
        }
      } else {
        if(sidx < 32){
          sm = sidx >> 4; sk = sidx & 15;
          pv = *(const uint4*)(h1in + ((2*bid + sm)*512 + t + 1)*128 + sk*8);
        }
      }
    }

    // ---- A fragments from current buffer (rows duplicated mod 2: harmless)
    bf8 Af[KT];
    {
      const u16* ar = &Abuf[cur][(l15 & 1)*RS + quad*8];
#pragma unroll
      for(int kt = 0; kt < KT; kt++) Af[kt] = *(const bf8*)(ar + kt*32);
    }

    // ---- MFMA: 4 independent acc chains (one per gate)
    f4 acc[4];
#pragma unroll
    for(int q = 0; q < 4; q++){ f4 z = {0.f,0.f,0.f,0.f}; acc[q] = z; }
#pragma unroll
    for(int kt = 0; kt < KT; kt++){
#pragma unroll
      for(int q = 0; q < 4; q++){
        acc[q] = __builtin_amdgcn_mfma_f32_16x16x32_bf16(Af[kt], Bf[q][kt], acc[q], 0, 0, 0);
      }
    }

    // ---- in-register cell update: lanes 0-15 hold rows 0,1 in regs 0,1
    if(lane < 16){
      // row 0
      float i0 = sigm_ps(acc[0][0] + b4[0]);
      float f0 = sigm_ps(acc[1][0] + b4[1]);
      float g0 = 2.0f * sigm_ps(acc[2][0] + b4[2]) - 1.0f;
      float o0 = sigm_ps(acc[3][0] + b4[3]);
      c0 = f0*c0 + i0*g0;
      h0r = o0 * (2.0f * sigm_ps(c0 * (2.0f * LOG2E)) - 1.0f);
      // row 1
      float i1 = sigm_ps(acc[0][1] + b4[0]);
      float f1 = sigm_ps(acc[1][1] + b4[1]);
      float g1 = 2.0f * sigm_ps(acc[2][1] + b4[2]) - 1.0f;
      float o1 = sigm_ps(acc[3][1] + b4[3]);
      c1 = f1*c1 + i1*g1;
      h1r = o1 * (2.0f * sigm_ps(c1 * (2.0f * LOG2E)) - 1.0f);

      u16 hb0 = f2bf(h0r), hb1 = f2bf(h1r);
      Abuf[nxt][0*RS + j0] = hb0;
      Abuf[nxt][1*RS + j0] = hb1;
      if(IS_L0){
        h1out[((2*bid + 0)*512 + t)*128 + j0] = hb0;
        h1out[((2*bid + 1)*512 + t)*128 + j0] = hb1;
      }
    } else if(t < 511){
      // ---- stage prefetched t+1 input into next buffer
      if(IS_L0){
        if(sidx < 36) Abuf[nxt][sm*RS + 128 + sk] = f2bf(xv);
      } else {
        if(sidx < 32) *(uint4*)&Abuf[nxt][sm*RS + 128 + sk*8] = pv;
      }
    }
    __syncthreads();
  }

  // ---- fused FC head (L1 only), fp32
  if(!IS_L0){
    if(lane < 16){
      hfin[j0]       = h0r;
      hfin[128 + j0] = h1r;
    }
    __syncthreads();
    if(tid < 128){
      int m = tid >> 6, v = tid & 63;
      float s = bfc1[v];
      for(int j = 0; j < 128; j++) s = fmaf(Wfc1[v*128 + j], hfin[m*128 + j], s);
      s = fmaxf(s, 0.0f);
      float term = s * Wfc2[v];
#pragma unroll
      for(int off = 32; off > 0; off >>= 1) term += __shfl_down(term, off);
      if(v == 0){
        out[2*bid + m] = sigm_ps((term + bfc2[0]) * LOG2E);
      }
    }
  }
}

// ---------------------------------------------------------------------------
extern "C" void kernel_launch(void* const* d_in, const int* in_sizes, int n_in,
                              void* d_out, int out_size, void* d_ws, size_t ws_size,
                              hipStream_t stream){
  const float* x    = (const float*)d_in[0];
  const float* Wih0 = (const float*)d_in[1];
  const float* Whh0 = (const float*)d_in[2];
  const float* bih0 = (const float*)d_in[3];
  const float* bhh0 = (const float*)d_in[4];
  const float* Wih1 = (const float*)d_in[5];
  const float* Whh1 = (const float*)d_in[6];
  const float* bih1 = (const float*)d_in[7];
  const float* bhh1 = (const float*)d_in[8];
  const float* Wfc1 = (const float*)d_in[9];
  const float* bfc1 = (const float*)d_in[10];
  const float* Wfc2 = (const float*)d_in[11];
  const float* bfc2 = (const float*)d_in[12];

  char* ws = (char*)d_ws;
  u16*   W0c   = (u16*)(ws);                       // 512*160*2 = 163840 B
  u16*   W1c   = (u16*)(ws + 163840);              // 512*256*2 = 262144 B
  float* bias0 = (float*)(ws + 163840 + 262144);   // 2048 B
  float* bias1 = bias0 + 512;                      // 2048 B
  u16*   h1    = (u16*)(ws + 163840 + 262144 + 4096);  // 64 MiB

  prep_kernel<<<dim3(512), dim3(64), 0, stream>>>(Wih0, Whh0, bih0, bhh0,
                                                  Wih1, Whh1, bih1, bhh1,
                                                  W0c, W1c, bias0, bias1);

  // Layer 0: K=160 (KT=5), row stride 168 (+8 pad)
  lstm_kernel<5, 168, true><<<dim3(256), dim3(512), 0, stream>>>(
      W0c, bias0, x, nullptr, h1,
      nullptr, nullptr, nullptr, nullptr, nullptr);

  // Layer 1: K=256 (KT=8), row stride 264 (+8 pad); fused FC head
  lstm_kernel<8, 264, false><<<dim3(256), dim3(512), 0, stream>>>(
      W1c, bias1, nullptr, h1, nullptr,
      Wfc1, bfc1, Wfc2, bfc2, (float*)d_out);
}

// Round 4
// 857.425 us; speedup vs baseline: 1.0411x; 1.0411x over previous
//
#include <hip/hip_runtime.h>
#include <stdint.h>

typedef short bf8 __attribute__((ext_vector_type(8)));   // 8 bf16 (4 VGPRs)
typedef float f4  __attribute__((ext_vector_type(4)));   // MFMA acc
typedef unsigned short u16;
typedef unsigned long long u64;

#define LOG2E 1.4426950408889634f

__device__ __forceinline__ u16 f2bf(float f){
  uint32_t u = __builtin_bit_cast(uint32_t, f);
  u += 0x7fffu + ((u >> 16) & 1u);
  return (u16)(u >> 16);
}
// sigmoid of value pre-scaled by log2e: 1/(1+2^-a)
__device__ __forceinline__ float sigm_ps(float a){
  return __builtin_amdgcn_rcpf(1.0f + __builtin_amdgcn_exp2f(-a));
}

// ---------------------------------------------------------------------------
// Prep: prescaled bf16 weights W0c[512][160]=[Whh0|Wih0|0], W1c[512][256]=
// [Whh1|Wih1]; rows scaled log2e (i,f,o) / 2*log2e (g); prescaled biases;
// zero the progress counters (ws is poisoned 0xAA before every launch!).
// ---------------------------------------------------------------------------
__global__ void prep_kernel(const float* __restrict__ Wih0, const float* __restrict__ Whh0,
                            const float* __restrict__ bih0, const float* __restrict__ bhh0,
                            const float* __restrict__ Wih1, const float* __restrict__ Whh1,
                            const float* __restrict__ bih1, const float* __restrict__ bhh1,
                            u16* __restrict__ W0c, u16* __restrict__ W1c,
                            float* __restrict__ bias0, float* __restrict__ bias1,
                            int* __restrict__ prog){
  int g = blockIdx.x;      // gate row 0..511
  int t = threadIdx.x;     // 0..63
  float s = (g >= 256 && g < 384) ? 2.0f * LOG2E : LOG2E;
  for(int k = t; k < 160; k += 64){
    float v = 0.0f;
    if(k < 128)      v = Whh0[g*128 + k];
    else if(k < 146) v = Wih0[g*18 + (k-128)];
    W0c[g*160 + k] = f2bf(v * s);
  }
  for(int k = t; k < 256; k += 64){
    float v = (k < 128) ? Whh1[g*128 + k] : Wih1[g*128 + (k-128)];
    W1c[g*256 + k] = f2bf(v * s);
  }
  if(t == 0){
    bias0[g] = (bih0[g] + bhh0[g]) * s;
    bias1[g] = (bih1[g] + bhh1[g]) * s;
  }
  if(g == 0 && t < 32) prog[t] = 0;
}

// ---------------------------------------------------------------------------
// Fused 2-layer LSTM, gate-major MFMA, producer/consumer overlap.
// 64 blocks x 512 threads. bid<32: L0-role (rows rb*16..+16), else L1-role.
// A = prescaled weights (static VGPR frags, M=gates), B = [h | x]/[h2|h1]
// from LDS (N=16 batch rows). Wave w owns M-tiles {w,w+8,w+16,w+24} = gate
// type q at comps [16w,16w+16). Lane (l15=row, quad): acc[q][r] = gate type
// q, comp j=16w+quad*4+r, row l15 -> fully in-register cell update.
// L0 publishes h1(t) with agent atomics + prog[rb]; L1 polls (lag-tolerant).
// ---------------------------------------------------------------------------
__global__ __launch_bounds__(512, 2)
void lstm_fused(const u16* __restrict__ Wc0, const u16* __restrict__ Wc1,
                const float* __restrict__ bias0, const float* __restrict__ bias1,
                const float* __restrict__ xin,   // (512,512,18) f32
                u64* __restrict__ h1g,           // [T][512 rows][32 u64] bf16x4
                int* __restrict__ prog,          // [32] per-rowblock progress
                const float* __restrict__ Wfc1, const float* __restrict__ bfc1,
                const float* __restrict__ Wfc2, const float* __restrict__ bfc2,
                float* __restrict__ out)         // (512,) f32
{
  __shared__ __align__(16) u16  hb[2][16][264];  // [buf][row][K-slots(+pad)]
  __shared__ __align__(16) float ffin[16][132];  // final h2 f32 for FC head

  const int tid  = threadIdx.x;
  const int wave = tid >> 6;
  const int lane = tid & 63;
  const int quad = lane >> 4;
  const int l15  = lane & 15;
  const bool isL0 = (blockIdx.x < 32);
  const int rb   = isL0 ? blockIdx.x : (blockIdx.x - 32);
  const int rowbase = rb * 16;

  // zero both LDS buffers (zeros double as h=0 init and K-padding)
  for(int i = tid; i < 2*16*264; i += 512) ((u16*)hb)[i] = 0;

  if(isL0){
    // ---------------- L0 role: K=160 = [h0(128) | x(18) | 0(14)], KT=5 ----
    bf8 A[4][5];
#pragma unroll
    for(int q = 0; q < 4; q++){
      const u16* wp = Wc0 + (u64)(128*q + 16*wave + l15)*160 + quad*8;
#pragma unroll
      for(int kt = 0; kt < 5; kt++) A[q][kt] = *(const bf8*)(wp + kt*32);
    }
    f4 bini[4];
#pragma unroll
    for(int q = 0; q < 4; q++) bini[q] = *(const f4*)(bias0 + 128*q + 16*wave + quad*4);
    float c[4] = {0.f,0.f,0.f,0.f};

    __syncthreads();
    // stage x(0)
    if(tid < 288){
      int r = tid/18, k = tid - 18*r;
      hb[0][r][128+k] = f2bf(xin[((u64)(rowbase+r)*512 + 0)*18 + k]);
    }
    __syncthreads();

    int sr = 0, sk = 0;
    if(tid < 288){ sr = tid/18; sk = tid - 18*sr; }

    for(int t = 0; t < 512; t++){
      const int cur = t & 1, nxt = cur ^ 1;
      // prefetch x(t+1)
      float xv = 0.f;
      if(tid < 288 && t < 511)
        xv = xin[((u64)(rowbase+sr)*512 + (t+1))*18 + sk];

      bf8 B[5];
      const u16* br = &hb[cur][l15][quad*8];
#pragma unroll
      for(int kt = 0; kt < 5; kt++) B[kt] = *(const bf8*)(br + kt*32);

      f4 acc[4];
#pragma unroll
      for(int q = 0; q < 4; q++) acc[q] = bini[q];
#pragma unroll
      for(int kt = 0; kt < 5; kt++){
#pragma unroll
        for(int q = 0; q < 4; q++)
          acc[q] = __builtin_amdgcn_mfma_f32_16x16x32_bf16(A[q][kt], B[kt], acc[q], 0,0,0);
      }

      // in-register update: comps j=16w+quad*4+r, row l15
      u64 hpack; u16* hp = (u16*)&hpack;
#pragma unroll
      for(int r = 0; r < 4; r++){
        float ig = sigm_ps(acc[0][r]);
        float fg = sigm_ps(acc[1][r]);
        float gg = 2.f*sigm_ps(acc[2][r]) - 1.f;
        float og = sigm_ps(acc[3][r]);
        c[r] = fg*c[r] + ig*gg;
        float th = 2.f*sigm_ps(c[r]*(2.f*LOG2E)) - 1.f;
        hp[r] = f2bf(og*th);
      }
      *(u64*)(&hb[nxt][l15][16*wave + quad*4]) = hpack;
      // publish h1(t) device-visible
      __hip_atomic_store(h1g + ((u64)t*512 + rowbase + l15)*32 + 4*wave + quad,
                         hpack, __ATOMIC_RELAXED, __HIP_MEMORY_SCOPE_AGENT);
      if(tid < 288 && t < 511) hb[nxt][sr][128+sk] = f2bf(xv);
      __syncthreads();   // drains vmcnt -> all h1 stores complete before publish
      if(tid == 0)
        __hip_atomic_store(prog + rb, t + 1, __ATOMIC_RELEASE, __HIP_MEMORY_SCOPE_AGENT);
    }
  } else {
    // ---------------- L1 role: K=256 = [h2(128) | h1(128)], KT=8 ----------
    bf8 A[4][8];
#pragma unroll
    for(int q = 0; q < 4; q++){
      const u16* wp = Wc1 + (u64)(128*q + 16*wave + l15)*256 + quad*8;
#pragma unroll
      for(int kt = 0; kt < 8; kt++) A[q][kt] = *(const bf8*)(wp + kt*32);
    }
    f4 bini[4];
#pragma unroll
    for(int q = 0; q < 4; q++) bini[q] = *(const f4*)(bias1 + 128*q + 16*wave + quad*4);
    float c[4] = {0.f,0.f,0.f,0.f};

    const int pr = tid >> 5;          // staging row
    const int pu = tid & 31;          // staging u64-chunk (4 comps)
    int seen = 0;

    __syncthreads();
    // wait for h1(0), stage into buf0
    while(seen < 1){
      seen = __hip_atomic_load(prog + rb, __ATOMIC_ACQUIRE, __HIP_MEMORY_SCOPE_AGENT);
      if(seen < 1) __builtin_amdgcn_s_sleep(8);
    }
    {
      u64 v = __hip_atomic_load(h1g + ((u64)0*512 + rowbase + pr)*32 + pu,
                                __ATOMIC_RELAXED, __HIP_MEMORY_SCOPE_AGENT);
      *(u64*)(&hb[0][pr][128 + pu*4]) = v;
    }
    __syncthreads();

    float hv[4];
    for(int t = 0; t < 512; t++){
      const int cur = t & 1, nxt = cur ^ 1;
      // ensure h1(t+1) published, then prefetch it
      u64 pv = 0;
      if(t < 511){
        const int need = t + 2;
        while(seen < need){
          seen = __hip_atomic_load(prog + rb, __ATOMIC_ACQUIRE, __HIP_MEMORY_SCOPE_AGENT);
          if(seen < need) __builtin_amdgcn_s_sleep(8);
        }
        pv = __hip_atomic_load(h1g + ((u64)(t+1)*512 + rowbase + pr)*32 + pu,
                               __ATOMIC_RELAXED, __HIP_MEMORY_SCOPE_AGENT);
      }

      bf8 B[8];
      const u16* br = &hb[cur][l15][quad*8];
#pragma unroll
      for(int kt = 0; kt < 8; kt++) B[kt] = *(const bf8*)(br + kt*32);

      f4 acc[4];
#pragma unroll
      for(int q = 0; q < 4; q++) acc[q] = bini[q];
#pragma unroll
      for(int kt = 0; kt < 8; kt++){
#pragma unroll
        for(int q = 0; q < 4; q++)
          acc[q] = __builtin_amdgcn_mfma_f32_16x16x32_bf16(A[q][kt], B[kt], acc[q], 0,0,0);
      }

      u64 hpack; u16* hp = (u16*)&hpack;
#pragma unroll
      for(int r = 0; r < 4; r++){
        float ig = sigm_ps(acc[0][r]);
        float fg = sigm_ps(acc[1][r]);
        float gg = 2.f*sigm_ps(acc[2][r]) - 1.f;
        float og = sigm_ps(acc[3][r]);
        c[r] = fg*c[r] + ig*gg;
        float th = 2.f*sigm_ps(c[r]*(2.f*LOG2E)) - 1.f;
        hv[r] = og*th;
        hp[r] = f2bf(hv[r]);
      }
      *(u64*)(&hb[nxt][l15][16*wave + quad*4]) = hpack;
      if(t < 511) *(u64*)(&hb[nxt][pr][128 + pu*4]) = pv;
      __syncthreads();
    }
    // stash final h2 (f32) for FC head
#pragma unroll
    for(int r = 0; r < 4; r++) ffin[l15][16*wave + quad*4 + r] = hv[r];
    __syncthreads();

    // ---- FC head: per row r, 64 hidden, 32 threads x 2v each
    {
      int r = tid >> 5, u = tid & 31;
      float s0 = bfc1[2*u], s1 = bfc1[2*u+1];
      const float* w0 = Wfc1 + (2*u)*128;
      const float* w1 = Wfc1 + (2*u+1)*128;
      for(int j = 0; j < 128; j++){
        float h = ffin[r][j];
        s0 = fmaf(w0[j], h, s0);
        s1 = fmaf(w1[j], h, s1);
      }
      float term = fmaxf(s0, 0.f)*Wfc2[2*u] + fmaxf(s1, 0.f)*Wfc2[2*u+1];
#pragma unroll
      for(int off = 16; off > 0; off >>= 1) term += __shfl_down(term, off, 32);
      if(u == 0) out[rowbase + r] = sigm_ps((term + bfc2[0]) * LOG2E);
    }
  }
}

// ---------------------------------------------------------------------------
extern "C" void kernel_launch(void* const* d_in, const int* in_sizes, int n_in,
                              void* d_out, int out_size, void* d_ws, size_t ws_size,
                              hipStream_t stream){
  const float* x    = (const float*)d_in[0];
  const float* Wih0 = (const float*)d_in[1];
  const float* Whh0 = (const float*)d_in[2];
  const float* bih0 = (const float*)d_in[3];
  const float* bhh0 = (const float*)d_in[4];
  const float* Wih1 = (const float*)d_in[5];
  const float* Whh1 = (const float*)d_in[6];
  const float* bih1 = (const float*)d_in[7];
  const float* bhh1 = (const float*)d_in[8];
  const float* Wfc1 = (const float*)d_in[9];
  const float* bfc1 = (const float*)d_in[10];
  const float* Wfc2 = (const float*)d_in[11];
  const float* bfc2 = (const float*)d_in[12];

  char* ws = (char*)d_ws;
  u16*   W0c   = (u16*)(ws);                       // 512*160*2 = 163840 B
  u16*   W1c   = (u16*)(ws + 163840);              // 512*256*2 = 262144 B
  float* bias0 = (float*)(ws + 163840 + 262144);   // 2048 B
  float* bias1 = bias0 + 512;                      // 2048 B
  int*   prog  = (int*)(ws + 163840 + 262144 + 4096);  // 128 B (pad to 256)
  u64*   h1g   = (u64*)(ws + 163840 + 262144 + 4096 + 256); // 64 MiB

  prep_kernel<<<dim3(512), dim3(64), 0, stream>>>(Wih0, Whh0, bih0, bhh0,
                                                  Wih1, Whh1, bih1, bhh1,
                                                  W0c, W1c, bias0, bias1, prog);

  lstm_fused<<<dim3(64), dim3(512), 0, stream>>>(
      W0c, W1c, bias0, bias1, x, h1g, prog,
      Wfc1, bfc1, Wfc2, bfc2, (float*)d_out);
}